// Round 8
// baseline (3923.892 us; speedup 1.0000x reference)
//
#include <hip/hip_runtime.h>
#include <math.h>

#define B 32
#define T 32
#define O_DIM 256
#define H_DIM 512
#define HS 64
#define MS 2048
#define NCOL 516
#define NCH 32          // 64-row softmax chunks

typedef __attribute__((ext_vector_type(4))) float f4;

__device__ __forceinline__ float sigm(float x){ return 1.0f/(1.0f+__expf(-x)); }
__device__ __forceinline__ float hsum(f4 v){ return (v.x + v.y) + (v.z + v.w); }

// ---------------- prep kernels ----------------
__global__ __launch_bounds__(256) void k_transpose_t(float* __restrict__ dst,
                                                     const float* __restrict__ src,
                                                     int N, int K){
  __shared__ float tile[32][33];
  int jb = blockIdx.x*32, kb = blockIdx.y*32;
  int tj = threadIdx.x & 31, tk = threadIdx.x >> 5;
  #pragma unroll
  for (int p = 0; p < 4; ++p){
    int j = jb + tk + p*8, k = kb + tj;
    if (j < N && k < K) tile[tk + p*8][tj] = src[j*K + k];
  }
  __syncthreads();
  #pragma unroll
  for (int p = 0; p < 4; ++p){
    int k = kb + tk + p*8, j = jb + tj;
    if (j < N && k < K) dst[k*N + j] = tile[tj][tk + p*8];
  }
}

__global__ __launch_bounds__(256) void k_ghead(float* __restrict__ dst,
                                               const float* __restrict__ W_head){
  int idx = blockIdx.x*256 + threadIdx.x;     // col*512 + k
  if (idx >= 520*512) return;
  int col = idx >> 9, k = idx & 511;
  float v = 0.f;
  if (col < NCOL){ int n = col/129, c = col%129; v = W_head[((size_t)n*2115 + c)*512 + k]; }
  dst[idx] = v;
}

__global__ __launch_bounds__(256) void k_xt(f4* __restrict__ XT4,
                                            const float* __restrict__ x){
  int idx = blockIdx.x*256 + threadIdx.x;     // t*2048 + k4*32 + b
  int b = idx & 31, k4 = (idx >> 5) & 63, t = idx >> 11;
  XT4[idx] = ((const f4*)x)[(size_t)(b*T + t)*64 + k4];
}

// ---------------- persistent kernel ----------------
struct Args {
  const float *W_ih, *W_hh, *b_ih, *b_hh, *b_head, *b_out;
  const float *WT_HD2, *WT_OUT;
  const f4 *XT4;
  float *out, *MEM, *HF, *CF;
  float *SW, *PART, *PREAD, *HPT, *READT, *HHT, *RHIST, *WST, *WKS;
  unsigned *cnt;
};

union LS {
  struct { float gl[8][33]; } a;
  struct { float red[256]; } b;
  struct { float keys[8][64]; float mc[64][68]; float sc[8][64];
           float red[8][32]; float cmx[8]; float ew[4][64];
           f4 wkp[4][16]; float gmp[4], facp[4]; } c;
  struct { float gm2[4], dn2[4]; } d;
  struct { float gm[4], fac[4]; f4 wk4[4][16]; float ew[4][256]; } fl;
  struct { float A[16][260]; } o;
};

__device__ __forceinline__ void gbar(unsigned* cnt, unsigned& gen){
  __syncthreads();
  if (threadIdx.x == 0){
    ++gen;
    __hip_atomic_fetch_add(cnt, 1u, __ATOMIC_RELEASE, __HIP_MEMORY_SCOPE_AGENT);
    unsigned tgt = 256u * gen;
    while (__hip_atomic_load(cnt, __ATOMIC_RELAXED, __HIP_MEMORY_SCOPE_AGENT) < tgt)
      __builtin_amdgcn_s_sleep(2);
    (void)__hip_atomic_load(cnt, __ATOMIC_ACQUIRE, __HIP_MEMORY_SCOPE_AGENT);
  }
  __syncthreads();
}

__global__ __launch_bounds__(256, 1) void ntm_persist(Args g){
  const int bid = blockIdx.x, tid = threadIdx.x;
  __shared__ f4 WL[2048];        // 8 gate rows x 256 f4 (W_ih|W_hh), 32 KB, persistent
  __shared__ LS u;
  unsigned gen = 0;

  // one-time: stage this block's 8 gate rows into LDS
  for (int idx = tid; idx < 2048; idx += 256){
    int rsub = idx >> 8, q = idx & 255;
    int gate = rsub & 3, jj = (rsub >> 2) & 1;
    int row = gate*512 + bid*2 + jj;
    WL[idx] = (q < 128) ? ((const f4*)g.W_ih)[(size_t)row*128 + q]
                        : ((const f4*)g.W_hh)[(size_t)row*128 + (q - 128)];
  }
  __syncthreads();

  const f4* READT4 = (const f4*)g.READT;
  const f4* HHT4   = (const f4*)g.HHT;
  f4* MEM4         = (f4*)g.MEM;

  for (int t = 0; t < T; ++t){
    // ======== PH_A: gates GEMM + LSTM ========
    {
      int b = tid & 31, rsub = tid >> 5;
      const f4* w = WL + rsub*256;
      const f4* xt4 = g.XT4 + (size_t)t*2048;
      f4 a0 = {0.f,0.f,0.f,0.f}, a1 = {0.f,0.f,0.f,0.f};
      #pragma unroll 4
      for (int k4 = 0; k4 < 64; k4 += 2){
        a0 += w[k4]   * xt4[k4*32 + b];
        a1 += w[k4+1] * xt4[(k4+1)*32 + b];
      }
      #pragma unroll 4
      for (int k4 = 0; k4 < 64; k4 += 2){
        a0 += w[64+k4]   * READT4[k4*32 + b];
        a1 += w[64+k4+1] * READT4[(k4+1)*32 + b];
      }
      if (t > 0){
        const f4* ht4 = HHT4 + (size_t)(t-1)*4096;
        #pragma unroll 4
        for (int k4 = 0; k4 < 128; k4 += 2){
          a0 += w[128+k4]   * ht4[k4*32 + b];
          a1 += w[128+k4+1] * ht4[(k4+1)*32 + b];
        }
      }
      int gate = rsub & 3, jj = rsub >> 2;
      int row = gate*512 + bid*2 + jj;
      float acc = hsum(a0 + a1) + g.b_ih[row] + g.b_hh[row];
      __syncthreads();           // protect union vs previous phase usage
      u.a.gl[rsub][tid & 31] = acc;
    }
    __syncthreads();
    if (tid < 64){
      int b2 = tid & 31, jj2 = tid >> 5;
      int j2 = bid*2 + jj2;
      float gi = u.a.gl[jj2*4+0][b2], gf = u.a.gl[jj2*4+1][b2];
      float gg = u.a.gl[jj2*4+2][b2], go = u.a.gl[jj2*4+3][b2];
      float c = sigm(gf)*g.CF[b2*512+j2] + sigm(gi)*tanhf(gg);
      float h = sigm(go)*tanhf(c);
      g.CF[b2*512+j2] = c;
      g.HHT[((size_t)t*128 + (j2>>2))*128 + b2*4 + (j2&3)] = h;
    }
    gbar(g.cnt, gen);

    // ======== PH_B: head projection (used cols) ========
    if (bid < 130){
      int b = tid & 31, cs = (tid>>5)&3, khalf = tid>>7;
      int col = bid*4 + cs;
      const f4* hT4 = HHT4 + (size_t)t*4096 + khalf*2048;
      const f4* w4  = (const f4*)(g.WT_HD2 + (size_t)col*512 + khalf*256);
      f4 acc4 = {0.f, 0.f, 0.f, 0.f};
      #pragma unroll 4
      for (int k4 = 0; k4 < 64; ++k4)
        acc4 += w4[k4] * hT4[k4*32 + b];
      u.b.red[tid] = hsum(acc4);
      __syncthreads();
      if (khalf == 0){
        float v = u.b.red[tid] + u.b.red[tid + 128];
        if (col < NCOL){ int n = col/129, c = col%129; v += g.b_head[n*2115 + c]; }
        g.HPT[col*32 + b] = v;
      }
    }
    gbar(g.cnt, gen);

    // ======== PH_C: deferred mem-update + scores + partials + partial reads ========
    {
      int xcd = bid & 7, t2 = bid >> 3;
      int b = xcd*4 + (t2 & 3), ch8 = t2 >> 2;
      for (int idx = tid; idx < 512; idx += 256){
        int kk = idx >> 6, e = idx & 63;
        int n = kk & 3;
        int c = (kk >= 4) ? (64 + e) : e;
        u.c.keys[kk][e] = g.HPT[(n*129 + c)*32 + b];
      }
      if (t > 0){
        if (tid < 64){
          int n = tid >> 4, e4 = tid & 15;
          u.c.wkp[n][e4] = ((const f4*)g.WKS)[(b*4 + n)*16 + e4];
        }
        if (tid < 4){ u.c.gmp[tid] = g.WST[b*8 + tid*2]; u.c.facp[tid] = g.WST[b*8 + tid*2 + 1]; }
      }
      for (int sub = 0; sub < 4; ++sub){
        int ch = ch8*4 + sub;
        __syncthreads();
        for (int idx = tid; idx < 64*16; idx += 256){
          int m = idx >> 4, e4 = idx & 15;
          ((f4*)&u.c.mc[m][0])[e4] = MEM4[((size_t)b*MS + ch*64 + m)*16 + e4];
        }
        if (t > 0){
          int n = tid >> 6, m = tid & 63;
          float s = g.SW[((size_t)b*4 + n)*MS + ch*64 + m];
          u.c.ew[n][m] = __expf(s - u.c.gmp[n]) * u.c.facp[n];
        }
        __syncthreads();
        if (t > 0){
          for (int idx = tid; idx < 1024; idx += 256){
            int m = idx >> 4, e4 = idx & 15;
            f4 v = ((f4*)&u.c.mc[m][0])[e4];
            v += u.c.ew[0][m]*u.c.wkp[0][e4] + u.c.ew[1][m]*u.c.wkp[1][e4]
               + u.c.ew[2][m]*u.c.wkp[2][e4] + u.c.ew[3][m]*u.c.wkp[3][e4];
            ((f4*)&u.c.mc[m][0])[e4] = v;
            MEM4[((size_t)b*MS + ch*64 + m)*16 + e4] = v;
          }
          __syncthreads();
        }
        {
          int m = tid & 63, kp = tid >> 6;
          const f4* mrow4 = (const f4*)&u.c.mc[m][0];
          int k0 = kp*2, k1 = kp*2+1;
          f4 s0v = {0.f,0.f,0.f,0.f}, s1v = {0.f,0.f,0.f,0.f};
          #pragma unroll 4
          for (int e4 = 0; e4 < 16; ++e4){
            f4 mv = mrow4[e4];
            s0v += mv * (*(const f4*)&u.c.keys[k0][e4*4]);
            s1v += mv * (*(const f4*)&u.c.keys[k1][e4*4]);
          }
          float s0 = hsum(s0v)*0.125f, s1 = hsum(s1v)*0.125f;
          u.c.sc[k0][m] = s0; u.c.sc[k1][m] = s1;
          if (kp >= 2){
            float* swp = g.SW + ((size_t)b*4 + (k0-4))*MS + ch*64 + m;
            swp[0] = s0; swp[MS] = s1;
          }
        }
        __syncthreads();
        {
          int kk = tid >> 5, j = tid & 31;
          u.c.red[kk][j] = fmaxf(u.c.sc[kk][j], u.c.sc[kk][j+32]);
        }
        __syncthreads();
        if (tid < 8){
          float mx = u.c.red[tid][0];
          for (int j = 1; j < 32; ++j) mx = fmaxf(mx, u.c.red[tid][j]);
          u.c.cmx[tid] = mx;
        }
        __syncthreads();
        {
          int kk = tid >> 5, j = tid & 31;
          float m0 = u.c.cmx[kk];
          float e0 = __expf(u.c.sc[kk][j] - m0);
          float e1 = __expf(u.c.sc[kk][j+32] - m0);
          if (kk < 4){ u.c.sc[kk][j] = e0; u.c.sc[kk][j+32] = e1; }
          u.c.red[kk][j] = e0 + e1;
        }
        __syncthreads();
        if (tid < 8){
          float s = 0.f;
          for (int j = 0; j < 32; ++j) s += u.c.red[tid][j];
          float* pp = g.PART + (((size_t)b*NCH + ch)*8 + tid)*2;
          pp[0] = u.c.cmx[tid]; pp[1] = s;
        }
        {
          int n = tid >> 6, e = tid & 63;
          float pr = 0.f;
          for (int m = 0; m < 64; ++m) pr += u.c.sc[n][m] * u.c.mc[m][e];
          g.PREAD[(((size_t)b*NCH + ch)*4 + n)*64 + e] = pr;
        }
      }
    }
    gbar(g.cnt, gen);

    // ======== PH_D: read merge + write stats + wk save (+HF copy) ========
    if (bid < 32){
      int b = bid;
      if (tid < 4){
        int kk = 4 + tid;
        const float* pp = g.PART + ((size_t)b*NCH*8 + kk)*2;
        float mx = -1e30f;
        for (int ch = 0; ch < NCH; ++ch) mx = fmaxf(mx, pp[ch*16]);
        float d = 0.f;
        for (int ch = 0; ch < NCH; ++ch) d += pp[ch*16+1]*__expf(pp[ch*16] - mx);
        float st = sigm(g.HPT[(tid*129 + 128)*32 + b]);
        g.WST[b*8 + tid*2]     = mx;
        g.WST[b*8 + tid*2 + 1] = st / d;
      }
      {
        int n = tid >> 6, e = tid & 63;
        g.WKS[(b*4 + n)*64 + e] = g.HPT[(n*129 + 64 + e)*32 + b];
      }
      if (tid < 4){
        const float* pp = g.PART + ((size_t)b*NCH*8 + tid)*2;
        float mx = -1e30f;
        for (int ch = 0; ch < NCH; ++ch) mx = fmaxf(mx, pp[ch*16]);
        float d = 0.f;
        for (int ch = 0; ch < NCH; ++ch) d += pp[ch*16+1]*__expf(pp[ch*16] - mx);
        u.d.gm2[tid] = mx; u.d.dn2[tid] = d;
      }
      __syncthreads();
      {
        int n = tid >> 6, e = tid & 63;
        float gmn = u.d.gm2[n], dnn = u.d.dn2[n];
        float r = 0.f;
        for (int ch = 0; ch < NCH; ++ch){
          float cm = g.PART[(((size_t)b*NCH + ch)*8 + n)*2];
          r += g.PREAD[(((size_t)b*NCH + ch)*4 + n)*64 + e] * __expf(cm - gmn);
        }
        r /= dnn;
        int k = n*64 + e;
        g.READT[(k>>2)*128 + b*4 + (k&3)] = r;
        g.RHIST[((size_t)t*64 + (k>>2))*128 + b*4 + (k&3)] = r;
      }
      if (t == T-1){
        int i = bid*256 + tid;
        if (i < 4096){
          int j4 = i & 127, bb = i >> 7;
          ((f4*)g.HF)[i] = HHT4[((size_t)(T-1)*128 + j4)*32 + bb];
        }
      }
    }
    gbar(g.cnt, gen);
  }

  // ======== tail 1: final mem-update flush (t = T-1) ========
  {
    int xcd = bid & 7, t2 = bid >> 3;
    int b = xcd*4 + (t2 & 3), sub = t2 >> 2;
    if (tid < 4){ u.fl.gm[tid] = g.WST[b*8 + tid*2]; u.fl.fac[tid] = g.WST[b*8 + tid*2 + 1]; }
    if (tid < 64){
      int n = tid >> 4, e4 = tid & 15;
      u.fl.wk4[n][e4] = ((const f4*)g.WKS)[(b*4 + n)*16 + e4];
    }
    __syncthreads();
    for (int idx = tid; idx < 1024; idx += 256){
      int n = idx >> 8, m = idx & 255;
      float s = g.SW[((size_t)b*4 + n)*MS + sub*256 + m];
      u.fl.ew[n][m] = __expf(s - u.fl.gm[n]) * u.fl.fac[n];
    }
    __syncthreads();
    {
      int e4 = tid & 15, ms = tid >> 4;
      f4 k0 = u.fl.wk4[0][e4], k1 = u.fl.wk4[1][e4],
         k2 = u.fl.wk4[2][e4], k3 = u.fl.wk4[3][e4];
      #pragma unroll 2
      for (int it = 0; it < 16; ++it){
        int m = it*16 + ms;
        float w0 = u.fl.ew[0][m], w1 = u.fl.ew[1][m];
        float w2 = u.fl.ew[2][m], w3 = u.fl.ew[3][m];
        f4* p = MEM4 + ((size_t)b*MS + sub*256 + m)*16 + e4;
        f4 v = *p;
        v += w0*k0 + w1*k1 + w2*k2 + w3*k3;
        *p = v;
      }
    }
  }

  // ======== tail 2: batched output GEMM (1024 x 256, K=768) ========
  {
    const f4* RHIST4 = (const f4*)g.RHIST;
    const f4* W4 = (const f4*)g.WT_OUT;
    int nt = bid & 3, mt = bid >> 2;
    int rl = tid & 15, og = tid >> 4;
    int o = nt*64 + og*4, o4 = o >> 2;
    f4 a0 = {0.f,0.f,0.f,0.f}, a1 = a0, a2 = a0, a3 = a0;
    for (int kc = 0; kc < 3; ++kc){
      __syncthreads();
      for (int idx = tid; idx < 1024; idx += 256){
        int r = idx >> 6, k4 = idx & 63;
        int row = mt*16 + r;
        int bb = row >> 5, tt = row & 31;
        int kg4 = kc*64 + k4;
        f4 v = (kg4 < 128)
          ? HHT4[((size_t)tt*128 + kg4)*32 + bb]
          : RHIST4[((size_t)tt*64 + (kg4-128))*32 + bb];
        *(f4*)&u.o.A[r][k4*4] = v;
      }
      __syncthreads();
      const float* Ar = &u.o.A[rl][0];
      const f4* wp = W4 + (size_t)kc*256*64 + o4;
      #pragma unroll 2
      for (int k = 0; k < 256; k += 4){
        a0 += Ar[k]   * wp[(size_t)(k)*64];
        a1 += Ar[k+1] * wp[(size_t)(k+1)*64];
        a2 += Ar[k+2] * wp[(size_t)(k+2)*64];
        a3 += Ar[k+3] * wp[(size_t)(k+3)*64];
      }
    }
    int row = mt*16 + rl;
    f4 accv = (a0 + a1) + (a2 + a3);
    accv += *(const f4*)(g.b_out + o);
    *(f4*)(g.out + (size_t)row*O_DIM + o) = accv;
  }
}

extern "C" void kernel_launch(void* const* d_in, const int* in_sizes, int n_in,
                              void* d_out, int out_size, void* d_ws, size_t ws_size,
                              hipStream_t stream)
{
  const float* x      = (const float*)d_in[0];
  const float* W_ih   = (const float*)d_in[1];
  const float* W_hh   = (const float*)d_in[2];
  const float* b_ih   = (const float*)d_in[3];
  const float* b_hh   = (const float*)d_in[4];
  const float* W_head = (const float*)d_in[5];
  const float* b_head = (const float*)d_in[6];
  const float* W_out  = (const float*)d_in[7];
  const float* b_out  = (const float*)d_in[8];

  float* out = (float*)d_out;
  float* MEM = out + B*T*O_DIM;
  float* HF  = MEM + (size_t)B*MS*HS;
  float* CF  = HF + B*H_DIM;

  float* ws      = (float*)d_ws;
  float* WT_HD2  = ws;                          // 520*512
  float* WT_OUT  = WT_HD2 + 520*512;            // 768*256
  float* XT      = WT_OUT + 768*256;            // 262144
  float* SW      = XT     + 262144;             // 262144
  float* PART    = SW     + 262144;             // 16384
  float* PREAD   = PART   + 16384;              // 262144
  float* HPT     = PREAD  + 262144;             // 16640
  float* READT   = HPT    + 16640;              // 8192
  float* HHT     = READT  + 8192;               // 524288
  float* RHIST   = HHT    + 524288;             // 262144
  float* WST     = RHIST  + 262144;             // 256
  float* WKS     = WST    + 256;                // 8192
  unsigned* CNT  = (unsigned*)(WKS + 8192);

  (void)hipMemsetAsync(MEM, 0, ((size_t)B*MS*HS + 2*B*H_DIM)*sizeof(float), stream);
  (void)hipMemsetAsync(READT, 0, (size_t)8192*sizeof(float), stream);
  (void)hipMemsetAsync(CNT, 0, 64, stream);

  k_ghead<<<1040, 256, 0, stream>>>(WT_HD2, W_head);
  k_transpose_t<<<dim3(8, 24), 256, 0, stream>>>(WT_OUT, W_out, 256, 768);
  k_xt<<<256, 256, 0, stream>>>((f4*)XT, x);

  Args a;
  a.W_ih = W_ih; a.W_hh = W_hh; a.b_ih = b_ih; a.b_hh = b_hh;
  a.b_head = b_head; a.b_out = b_out;
  a.WT_HD2 = WT_HD2; a.WT_OUT = WT_OUT; a.XT4 = (const f4*)XT;
  a.out = out; a.MEM = MEM; a.HF = HF; a.CF = CF;
  a.SW = SW; a.PART = PART; a.PREAD = PREAD; a.HPT = HPT;
  a.READT = READT; a.HHT = HHT; a.RHIST = RHIST; a.WST = WST; a.WKS = WKS;
  a.cnt = CNT;

  ntm_persist<<<256, 256, 0, stream>>>(a);
}

// Round 9
// 2706.519 us; speedup vs baseline: 1.4498x; 1.4498x over previous
//
#include <hip/hip_runtime.h>
#include <math.h>

#define B 32
#define T 32
#define O_DIM 256
#define H_DIM 512
#define HS 64
#define MS 2048
#define NCOL 516
#define NCH 32          // 64-row softmax chunks

typedef __attribute__((ext_vector_type(4))) float f4;

__device__ __forceinline__ float sigm(float x){ return 1.0f/(1.0f+__expf(-x)); }
__device__ __forceinline__ float hsum(f4 v){ return (v.x + v.y) + (v.z + v.w); }

// ---------------- prep kernels ----------------
__global__ __launch_bounds__(256) void k_transpose_t(float* __restrict__ dst,
                                                     const float* __restrict__ src,
                                                     int N, int K){
  __shared__ float tile[32][33];
  int jb = blockIdx.x*32, kb = blockIdx.y*32;
  int tj = threadIdx.x & 31, tk = threadIdx.x >> 5;
  #pragma unroll
  for (int p = 0; p < 4; ++p){
    int j = jb + tk + p*8, k = kb + tj;
    if (j < N && k < K) tile[tk + p*8][tj] = src[j*K + k];
  }
  __syncthreads();
  #pragma unroll
  for (int p = 0; p < 4; ++p){
    int k = kb + tk + p*8, j = jb + tj;
    if (j < N && k < K) dst[k*N + j] = tile[tj][tk + p*8];
  }
}

__global__ __launch_bounds__(256) void k_ghead(float* __restrict__ dst,
                                               const float* __restrict__ W_head){
  int idx = blockIdx.x*256 + threadIdx.x;     // col*512 + k
  if (idx >= 520*512) return;
  int col = idx >> 9, k = idx & 511;
  float v = 0.f;
  if (col < NCOL){ int n = col/129, c = col%129; v = W_head[((size_t)n*2115 + c)*512 + k]; }
  dst[idx] = v;
}

__global__ __launch_bounds__(256) void k_xt(f4* __restrict__ XT4,
                                            const float* __restrict__ x){
  int idx = blockIdx.x*256 + threadIdx.x;     // t*2048 + k4*32 + b
  int b = idx & 31, k4 = (idx >> 5) & 63, t = idx >> 11;
  XT4[idx] = ((const f4*)x)[(size_t)(b*T + t)*64 + k4];
}

// ---------------- K1: gates GEMM + LSTM (256 blocks) ----------------
__global__ __launch_bounds__(256) void k_A(
    const f4* __restrict__ XT4, const float* __restrict__ W_ih,
    const float* __restrict__ W_hh, const float* __restrict__ b_ih,
    const float* __restrict__ b_hh, const f4* __restrict__ READT4,
    float* __restrict__ HHT, float* __restrict__ CF, int t)
{
  __shared__ f4 WS[8*256];     // 8 rows x (128 f4 W_ih + 128 f4 W_hh) = 32 KB
  __shared__ float gl[8][33];
  const int bid = blockIdx.x, tid = threadIdx.x;
  const f4* HHT4 = (const f4*)HHT;
  for (int idx = tid; idx < 2048; idx += 256){
    int rsub = idx >> 8, q = idx & 255;
    int gate = rsub & 3, jj = (rsub >> 2) & 1;
    int row = gate*512 + bid*2 + jj;
    WS[idx] = (q < 128) ? ((const f4*)W_ih)[(size_t)row*128 + q]
                        : ((const f4*)W_hh)[(size_t)row*128 + (q - 128)];
  }
  __syncthreads();
  {
    int b = tid & 31, rsub = tid >> 5;
    const f4* w = WS + rsub*256;
    const f4* xt4 = XT4 + (size_t)t*2048;
    f4 a0 = {0.f,0.f,0.f,0.f}, a1 = {0.f,0.f,0.f,0.f};
    #pragma unroll 4
    for (int k4 = 0; k4 < 64; k4 += 2){
      a0 += w[k4]   * xt4[k4*32 + b];
      a1 += w[k4+1] * xt4[(k4+1)*32 + b];
    }
    #pragma unroll 4
    for (int k4 = 0; k4 < 64; k4 += 2){
      a0 += w[64+k4]   * READT4[k4*32 + b];
      a1 += w[64+k4+1] * READT4[(k4+1)*32 + b];
    }
    if (t > 0){
      const f4* ht4 = HHT4 + (size_t)(t-1)*4096;
      #pragma unroll 4
      for (int k4 = 0; k4 < 128; k4 += 2){
        a0 += w[128+k4]   * ht4[k4*32 + b];
        a1 += w[128+k4+1] * ht4[(k4+1)*32 + b];
      }
    }
    int gate = rsub & 3, jj = rsub >> 2;
    int row = gate*512 + bid*2 + jj;
    gl[rsub][b] = hsum(a0 + a1) + b_ih[row] + b_hh[row];
  }
  __syncthreads();
  if (tid < 64){
    int b2 = tid & 31, jj2 = tid >> 5;
    int j2 = bid*2 + jj2;
    float gi = gl[jj2*4+0][b2], gf = gl[jj2*4+1][b2];
    float gg = gl[jj2*4+2][b2], go = gl[jj2*4+3][b2];
    float c = sigm(gf)*CF[b2*512+j2] + sigm(gi)*tanhf(gg);
    float h = sigm(go)*tanhf(c);
    CF[b2*512+j2] = c;
    HHT[((size_t)t*128 + (j2>>2))*128 + b2*4 + (j2&3)] = h;
  }
}

// ---- K2: head-proj producers (blocks 0..31) + CD consumers (32..287) ----
__global__ __launch_bounds__(256) void k_BCD(
    float* __restrict__ MEM, const float* __restrict__ HHT,
    const float* __restrict__ WT_HD2, const float* __restrict__ b_head,
    float* __restrict__ HPT, float* __restrict__ SW,
    float* __restrict__ PART, float* __restrict__ PREAD,
    float* __restrict__ READT, float* __restrict__ RHIST,
    float* __restrict__ WST, float* __restrict__ WKS,
    float* __restrict__ HF, unsigned* __restrict__ FLG,
    unsigned* __restrict__ CNT2, int t)
{
  __shared__ float hl[512];
  __shared__ float keys[8][64];
  __shared__ float mc[64][68];
  __shared__ float sc[8][64];
  __shared__ float red[8][32];
  __shared__ float cmx[8];
  __shared__ float ew[4][64];
  __shared__ f4 wkp[4][16];
  __shared__ float gmp[4], facp[4];
  __shared__ float mgm[4], mdn[4];
  __shared__ int lastf;
  const int bid = blockIdx.x, tid = threadIdx.x;
  const f4* HHT4 = (const f4*)HHT;
  f4* MEM4 = (f4*)MEM;

  if (bid < 32){
    // ---------- producer: head projection for batch b ----------
    int b = bid;
    for (int idx = tid; idx < 128; idx += 256)
      ((f4*)hl)[idx] = HHT4[(size_t)t*4096 + idx*32 + b];
    __syncthreads();
    for (int col = tid; col < NCOL; col += 256){
      const f4* w4 = (const f4*)(WT_HD2 + (size_t)col*512);
      const f4* h4 = (const f4*)hl;
      f4 a0 = {0.f,0.f,0.f,0.f}, a1 = {0.f,0.f,0.f,0.f};
      #pragma unroll 4
      for (int k4 = 0; k4 < 128; k4 += 2){
        a0 += w4[k4]   * h4[k4];
        a1 += w4[k4+1] * h4[k4+1];
      }
      int n = col/129, c = col%129;
      HPT[col*32 + b] = hsum(a0 + a1) + b_head[n*2115 + c];
    }
    if (t == T-1){
      int i = bid*256 + tid;
      if (i < 4096){
        int j4 = i & 127, bb = i >> 7;
        ((f4*)HF)[i] = HHT4[((size_t)(T-1)*128 + j4)*32 + bb];
      }
    }
    __syncthreads();   // drains this block's global stores (vmcnt) before release
    if (tid == 0)
      __hip_atomic_store(FLG + b*16, (unsigned)(t+1), __ATOMIC_RELEASE,
                         __HIP_MEMORY_SCOPE_AGENT);
    return;
  }

  // ---------- consumer: deferred mem-update + scores + partials ----------
  int cdid = bid - 32;
  int xcd = cdid & 7, t2 = cdid >> 3;
  int b = xcd*4 + (t2 & 3), ch8 = t2 >> 2;

  if (t > 0){
    if (tid < 64){
      int n = tid >> 4, e4 = tid & 15;
      wkp[n][e4] = ((const f4*)WKS)[(b*4 + n)*16 + e4];
    }
    if (tid < 4){ gmp[tid] = WST[b*8 + tid*2]; facp[tid] = WST[b*8 + tid*2 + 1]; }
  }
  if (tid == 0){
    while (__hip_atomic_load(FLG + b*16, __ATOMIC_RELAXED,
                             __HIP_MEMORY_SCOPE_AGENT) < (unsigned)(t+1))
      __builtin_amdgcn_s_sleep(1);
    (void)__hip_atomic_load(FLG + b*16, __ATOMIC_ACQUIRE,
                            __HIP_MEMORY_SCOPE_AGENT);
  }
  __syncthreads();

  for (int idx = tid; idx < 512; idx += 256){
    int kk = idx >> 6, e = idx & 63;
    int n = kk & 3;
    int c = (kk >= 4) ? (64 + e) : e;
    keys[kk][e] = HPT[(n*129 + c)*32 + b];
  }
  for (int sub = 0; sub < 4; ++sub){
    int ch = ch8*4 + sub;
    __syncthreads();
    for (int idx = tid; idx < 64*16; idx += 256){
      int m = idx >> 4, e4 = idx & 15;
      ((f4*)&mc[m][0])[e4] = MEM4[((size_t)b*MS + ch*64 + m)*16 + e4];
    }
    if (t > 0){
      int n = tid >> 6, m = tid & 63;
      float s = SW[((size_t)b*4 + n)*MS + ch*64 + m];
      ew[n][m] = __expf(s - gmp[n]) * facp[n];
    }
    __syncthreads();
    if (t > 0){
      for (int idx = tid; idx < 1024; idx += 256){
        int m = idx >> 4, e4 = idx & 15;
        f4 v = ((f4*)&mc[m][0])[e4];
        v += ew[0][m]*wkp[0][e4] + ew[1][m]*wkp[1][e4]
           + ew[2][m]*wkp[2][e4] + ew[3][m]*wkp[3][e4];
        ((f4*)&mc[m][0])[e4] = v;
        MEM4[((size_t)b*MS + ch*64 + m)*16 + e4] = v;
      }
      __syncthreads();
    }
    {
      int m = tid & 63, kp = tid >> 6;
      const f4* mrow4 = (const f4*)&mc[m][0];
      int k0 = kp*2, k1 = kp*2+1;
      f4 s0v = {0.f,0.f,0.f,0.f}, s1v = {0.f,0.f,0.f,0.f};
      #pragma unroll 4
      for (int e4 = 0; e4 < 16; ++e4){
        f4 mv = mrow4[e4];
        s0v += mv * (*(const f4*)&keys[k0][e4*4]);
        s1v += mv * (*(const f4*)&keys[k1][e4*4]);
      }
      float s0 = hsum(s0v)*0.125f, s1 = hsum(s1v)*0.125f;
      sc[k0][m] = s0; sc[k1][m] = s1;
      if (kp >= 2){
        float* swp = SW + ((size_t)b*4 + (k0-4))*MS + ch*64 + m;
        swp[0] = s0; swp[MS] = s1;
      }
    }
    __syncthreads();
    {
      int kk = tid >> 5, j = tid & 31;
      red[kk][j] = fmaxf(sc[kk][j], sc[kk][j+32]);
    }
    __syncthreads();
    if (tid < 8){
      float mx = red[tid][0];
      for (int j = 1; j < 32; ++j) mx = fmaxf(mx, red[tid][j]);
      cmx[tid] = mx;
    }
    __syncthreads();
    {
      int kk = tid >> 5, j = tid & 31;
      float m0 = cmx[kk];
      float e0 = __expf(sc[kk][j] - m0);
      float e1 = __expf(sc[kk][j+32] - m0);
      if (kk < 4){ sc[kk][j] = e0; sc[kk][j+32] = e1; }
      red[kk][j] = e0 + e1;
    }
    __syncthreads();
    if (tid < 8){
      float s = 0.f;
      for (int j = 0; j < 32; ++j) s += red[tid][j];
      float* pp = PART + (((size_t)b*NCH + ch)*8 + tid)*2;
      pp[0] = cmx[tid]; pp[1] = s;
    }
    {
      int n = tid >> 6, e = tid & 63;
      float pr = 0.f;
      for (int m = 0; m < 64; ++m) pr += sc[n][m] * mc[m][e];
      PREAD[(((size_t)b*NCH + ch)*4 + n)*64 + e] = pr;
    }
  }
  __syncthreads();   // drain PART/PREAD stores before the release-RMW
  if (tid == 0){
    unsigned old = __hip_atomic_fetch_add(CNT2 + b*16, 1u, __ATOMIC_ACQ_REL,
                                          __HIP_MEMORY_SCOPE_AGENT);
    lastf = ((old & 7u) == 7u) ? 1 : 0;
  }
  __syncthreads();
  if (!lastf) return;

  // ---------- last block of this b: read merge + write stats + wk save ----------
  if (tid < 4){
    int kk = 4 + tid;
    const float* pp = PART + ((size_t)b*NCH*8 + kk)*2;
    float mx = -1e30f;
    for (int ch = 0; ch < NCH; ++ch) mx = fmaxf(mx, pp[ch*16]);
    float d = 0.f;
    for (int ch = 0; ch < NCH; ++ch) d += pp[ch*16+1]*__expf(pp[ch*16] - mx);
    float st = sigm(HPT[(tid*129 + 128)*32 + b]);
    WST[b*8 + tid*2]     = mx;
    WST[b*8 + tid*2 + 1] = st / d;
  }
  {
    int n = tid >> 6, e = tid & 63;
    WKS[(b*4 + n)*64 + e] = HPT[(n*129 + 64 + e)*32 + b];
  }
  if (tid < 4){
    const float* pp = PART + ((size_t)b*NCH*8 + tid)*2;
    float mx = -1e30f;
    for (int ch = 0; ch < NCH; ++ch) mx = fmaxf(mx, pp[ch*16]);
    float d = 0.f;
    for (int ch = 0; ch < NCH; ++ch) d += pp[ch*16+1]*__expf(pp[ch*16] - mx);
    mgm[tid] = mx; mdn[tid] = d;
  }
  __syncthreads();
  {
    int n = tid >> 6, e = tid & 63;
    float gmn = mgm[n], dnn = mdn[n];
    float r = 0.f;
    for (int ch = 0; ch < NCH; ++ch){
      float cm = PART[(((size_t)b*NCH + ch)*8 + n)*2];
      r += PREAD[(((size_t)b*NCH + ch)*4 + n)*64 + e] * __expf(cm - gmn);
    }
    r /= dnn;
    int k = n*64 + e;
    READT[(k>>2)*128 + b*4 + (k&3)] = r;
    RHIST[((size_t)t*64 + (k>>2))*128 + b*4 + (k&3)] = r;
  }
}

// ---------------- final mem-update flush for t = T-1 (256 blocks) ----------------
__global__ __launch_bounds__(256) void k_flush(
    float* __restrict__ MEM, const float* __restrict__ SW,
    const float* __restrict__ WST, const float* __restrict__ WKS)
{
  __shared__ float gm[4], fac[4];
  __shared__ f4 wk4[4][16];
  __shared__ float ew[4][256];
  const int bid = blockIdx.x, tid = threadIdx.x;
  int xcd = bid & 7, t2 = bid >> 3;
  int b = xcd*4 + (t2 & 3), sub = t2 >> 2;
  if (tid < 4){ gm[tid] = WST[b*8 + tid*2]; fac[tid] = WST[b*8 + tid*2 + 1]; }
  if (tid < 64){
    int n = tid >> 4, e4 = tid & 15;
    wk4[n][e4] = ((const f4*)WKS)[(b*4 + n)*16 + e4];
  }
  __syncthreads();
  for (int idx = tid; idx < 1024; idx += 256){
    int n = idx >> 8, m = idx & 255;
    float s = SW[((size_t)b*4 + n)*MS + sub*256 + m];
    ew[n][m] = __expf(s - gm[n]) * fac[n];
  }
  __syncthreads();
  {
    int e4 = tid & 15, ms = tid >> 4;
    f4 k0 = wk4[0][e4], k1 = wk4[1][e4], k2 = wk4[2][e4], k3 = wk4[3][e4];
    #pragma unroll 2
    for (int it = 0; it < 16; ++it){
      int m = it*16 + ms;
      float w0 = ew[0][m], w1 = ew[1][m];
      float w2 = ew[2][m], w3 = ew[3][m];
      f4* p = (f4*)MEM + ((size_t)b*MS + sub*256 + m)*16 + e4;
      f4 v = *p;
      v += w0*k0 + w1*k1 + w2*k2 + w3*k3;
      *p = v;
    }
  }
}

// ---------------- final output GEMM (256 blocks) ----------------
__global__ __launch_bounds__(256) void k_out(
    const float* __restrict__ HHT, const float* __restrict__ RHIST,
    const float* __restrict__ WT_OUT, const float* __restrict__ b_out,
    float* __restrict__ out)
{
  __shared__ float A[16][260];
  const int bid = blockIdx.x, tid = threadIdx.x;
  const f4* HHT4 = (const f4*)HHT;
  const f4* RHIST4 = (const f4*)RHIST;
  const f4* W4 = (const f4*)WT_OUT;
  int nt = bid & 3, mt = bid >> 2;
  int rl = tid & 15, og = tid >> 4;
  int o = nt*64 + og*4, o4 = o >> 2;
  f4 a0 = {0.f,0.f,0.f,0.f}, a1 = a0, a2 = a0, a3 = a0;
  for (int kc = 0; kc < 3; ++kc){
    __syncthreads();
    for (int idx = tid; idx < 1024; idx += 256){
      int r = idx >> 6, k4 = idx & 63;
      int row = mt*16 + r;
      int bb = row >> 5, tt = row & 31;
      int kg4 = kc*64 + k4;
      f4 v = (kg4 < 128)
        ? HHT4[((size_t)tt*128 + kg4)*32 + bb]
        : RHIST4[((size_t)tt*64 + (kg4-128))*32 + bb];
      *(f4*)&A[r][k4*4] = v;
    }
    __syncthreads();
    const float* Ar = &A[rl][0];
    const f4* wp = W4 + (size_t)kc*256*64 + o4;
    #pragma unroll 2
    for (int k = 0; k < 256; k += 4){
      a0 += Ar[k]   * wp[(size_t)(k)*64];
      a1 += Ar[k+1] * wp[(size_t)(k+1)*64];
      a2 += Ar[k+2] * wp[(size_t)(k+2)*64];
      a3 += Ar[k+3] * wp[(size_t)(k+3)*64];
    }
  }
  int row = mt*16 + rl;
  f4 accv = (a0 + a1) + (a2 + a3);
  accv += *(const f4*)(b_out + o);
  *(f4*)(out + (size_t)row*O_DIM + o) = accv;
}

extern "C" void kernel_launch(void* const* d_in, const int* in_sizes, int n_in,
                              void* d_out, int out_size, void* d_ws, size_t ws_size,
                              hipStream_t stream)
{
  const float* x      = (const float*)d_in[0];
  const float* W_ih   = (const float*)d_in[1];
  const float* W_hh   = (const float*)d_in[2];
  const float* b_ih   = (const float*)d_in[3];
  const float* b_hh   = (const float*)d_in[4];
  const float* W_head = (const float*)d_in[5];
  const float* b_head = (const float*)d_in[6];
  const float* W_out  = (const float*)d_in[7];
  const float* b_out  = (const float*)d_in[8];

  float* out = (float*)d_out;
  float* MEM = out + B*T*O_DIM;
  float* HF  = MEM + (size_t)B*MS*HS;
  float* CF  = HF + B*H_DIM;

  float* ws      = (float*)d_ws;
  float* WT_HD2  = ws;                          // 520*512
  float* WT_OUT  = WT_HD2 + 520*512;            // 768*256
  float* XT      = WT_OUT + 768*256;            // 262144
  float* SW      = XT     + 262144;             // 262144
  float* PART    = SW     + 262144;             // 16384
  float* PREAD   = PART   + 16384;              // 262144
  float* HPT     = PREAD  + 262144;             // 16640
  float* READT   = HPT    + 16640;              // 8192
  float* HHT     = READT  + 8192;               // 524288
  float* RHIST   = HHT    + 524288;             // 262144
  float* WST     = RHIST  + 262144;             // 256
  float* WKS     = WST    + 256;                // 8192
  unsigned* FLG  = (unsigned*)(WKS + 8192);     // 32*16 u32
  unsigned* CNT2 = FLG + 32*16;                 // 32*16 u32

  (void)hipMemsetAsync(MEM, 0, ((size_t)B*MS*HS + 2*B*H_DIM)*sizeof(float), stream);
  (void)hipMemsetAsync(READT, 0, (size_t)8192*sizeof(float), stream);
  (void)hipMemsetAsync(FLG, 0, 2*32*16*sizeof(unsigned), stream);

  k_ghead<<<1040, 256, 0, stream>>>(WT_HD2, W_head);
  k_transpose_t<<<dim3(8, 24), 256, 0, stream>>>(WT_OUT, W_out, 256, 768);
  k_xt<<<256, 256, 0, stream>>>((f4*)XT, x);

  for (int t = 0; t < T; ++t){
    k_A<<<256, 256, 0, stream>>>((const f4*)XT, W_ih, W_hh, b_ih, b_hh,
                                 (const f4*)READT, HHT, CF, t);
    k_BCD<<<288, 256, 0, stream>>>(MEM, HHT, WT_HD2, b_head, HPT, SW, PART,
                                   PREAD, READT, RHIST, WST, WKS, HF,
                                   FLG, CNT2, t);
  }
  k_flush<<<256, 256, 0, stream>>>(MEM, SW, WST, WKS);
  k_out<<<256, 256, 0, stream>>>(HHT, RHIST, WT_OUT, b_out, out);
}

// Round 11
// 1966.330 us; speedup vs baseline: 1.9955x; 1.3764x over previous
//
#include <hip/hip_runtime.h>
#include <math.h>

#define B 32
#define T 32
#define O_DIM 256
#define H_DIM 512
#define HS 64
#define MS 2048
#define NCOL 516
#define NCH 32          // 64-row softmax chunks

typedef __attribute__((ext_vector_type(4))) float f4;

__device__ __forceinline__ float sigm(float x){ return 1.0f/(1.0f+__expf(-x)); }
__device__ __forceinline__ float hsum(f4 v){ return (v.x + v.y) + (v.z + v.w); }

// ---------------- prep kernels ----------------
__global__ __launch_bounds__(256) void k_transpose_t(float* __restrict__ dst,
                                                     const float* __restrict__ src,
                                                     int N, int K){
  __shared__ float tile[32][33];
  int jb = blockIdx.x*32, kb = blockIdx.y*32;
  int tj = threadIdx.x & 31, tk = threadIdx.x >> 5;
  #pragma unroll
  for (int p = 0; p < 4; ++p){
    int j = jb + tk + p*8, k = kb + tj;
    if (j < N && k < K) tile[tk + p*8][tj] = src[j*K + k];
  }
  __syncthreads();
  #pragma unroll
  for (int p = 0; p < 4; ++p){
    int k = kb + tk + p*8, j = jb + tj;
    if (j < N && k < K) dst[k*N + j] = tile[tj][tk + p*8];
  }
}

__global__ __launch_bounds__(256) void k_ghead(float* __restrict__ dst,
                                               const float* __restrict__ W_head){
  int idx = blockIdx.x*256 + threadIdx.x;     // col*512 + k
  if (idx >= 520*512) return;
  int col = idx >> 9, k = idx & 511;
  float v = 0.f;
  if (col < NCOL){ int n = col/129, c = col%129; v = W_head[((size_t)n*2115 + c)*512 + k]; }
  dst[idx] = v;
}

__global__ __launch_bounds__(256) void k_xt(f4* __restrict__ XT4,
                                            const float* __restrict__ x){
  int idx = blockIdx.x*256 + threadIdx.x;     // t*2048 + k4*32 + b
  int b = idx & 31, k4 = (idx >> 5) & 63, t = idx >> 11;
  XT4[idx] = ((const f4*)x)[(size_t)(b*T + t)*64 + k4];
}

// ---------------- K1: gates GEMM + LSTM (256 blocks) ----------------
__global__ __launch_bounds__(256) void k_A(
    const f4* __restrict__ XT4, const float* __restrict__ W_ih,
    const float* __restrict__ W_hh, const float* __restrict__ b_ih,
    const float* __restrict__ b_hh, const f4* __restrict__ READT4,
    float* __restrict__ HHT, float* __restrict__ CF, int t)
{
  __shared__ f4 WS[8*256];     // 8 rows x (128 f4 W_ih + 128 f4 W_hh) = 32 KB
  __shared__ float gl[8][33];
  const int bid = blockIdx.x, tid = threadIdx.x;
  const f4* HHT4 = (const f4*)HHT;
  for (int idx = tid; idx < 2048; idx += 256){
    int rsub = idx >> 8, q = idx & 255;
    int gate = rsub & 3, jj = (rsub >> 2) & 1;
    int row = gate*512 + bid*2 + jj;
    WS[idx] = (q < 128) ? ((const f4*)W_ih)[(size_t)row*128 + q]
                        : ((const f4*)W_hh)[(size_t)row*128 + (q - 128)];
  }
  __syncthreads();
  {
    int b = tid & 31, rsub = tid >> 5;
    const f4* w = WS + rsub*256;
    const f4* xt4 = XT4 + (size_t)t*2048;
    f4 a0 = {0.f,0.f,0.f,0.f}, a1 = {0.f,0.f,0.f,0.f};
    #pragma unroll 4
    for (int k4 = 0; k4 < 64; k4 += 2){
      a0 += w[k4]   * xt4[k4*32 + b];
      a1 += w[k4+1] * xt4[(k4+1)*32 + b];
    }
    #pragma unroll 4
    for (int k4 = 0; k4 < 64; k4 += 2){
      a0 += w[64+k4]   * READT4[k4*32 + b];
      a1 += w[64+k4+1] * READT4[(k4+1)*32 + b];
    }
    if (t > 0){
      const f4* ht4 = HHT4 + (size_t)(t-1)*4096;
      #pragma unroll 4
      for (int k4 = 0; k4 < 128; k4 += 2){
        a0 += w[128+k4]   * ht4[k4*32 + b];
        a1 += w[128+k4+1] * ht4[(k4+1)*32 + b];
      }
    }
    int gate = rsub & 3, jj = rsub >> 2;
    int row = gate*512 + bid*2 + jj;
    gl[rsub][b] = hsum(a0 + a1) + b_ih[row] + b_hh[row];
  }
  __syncthreads();
  if (tid < 64){
    int b2 = tid & 31, jj2 = tid >> 5;
    int j2 = bid*2 + jj2;
    float gi = gl[jj2*4+0][b2], gf = gl[jj2*4+1][b2];
    float gg = gl[jj2*4+2][b2], go = gl[jj2*4+3][b2];
    float c = sigm(gf)*CF[b2*512+j2] + sigm(gi)*tanhf(gg);
    float h = sigm(go)*tanhf(c);
    CF[b2*512+j2] = c;
    HHT[((size_t)t*128 + (j2>>2))*128 + b2*4 + (j2&3)] = h;
  }
}

// ---- K2 (256 blocks): per-block head-proj chunk producer, then CD consumer ----
// block (b, ch8): produces head cols [base, base+count) for b, signals CNT[b],
// spins for b's 8 producers, then CD on mem chunk-group ch8; last-of-8 merges.
__global__ __launch_bounds__(256) void k_BCD(
    float* __restrict__ MEM, const float* __restrict__ HHT,
    const float* __restrict__ WT_HD2, const float* __restrict__ b_head,
    float* __restrict__ HPT, float* __restrict__ SW,
    float* __restrict__ PART, float* __restrict__ PREAD,
    float* __restrict__ READT, float* __restrict__ RHIST,
    float* __restrict__ WST, float* __restrict__ WKS,
    float* __restrict__ HF, unsigned* __restrict__ CNT,
    unsigned* __restrict__ CNT2, int t)
{
  __shared__ float hl[512];
  __shared__ float redp[65][4];
  __shared__ float keys[8][64];
  __shared__ float mc[64][68];
  __shared__ float sc[8][64];
  __shared__ float red[8][32];
  __shared__ float cmx[8];
  __shared__ float ew[4][64];
  __shared__ f4 wkp[4][16];
  __shared__ float gmp[4], facp[4];
  __shared__ float mgm[4], mdn[4];
  __shared__ int lastf;
  const int bid = blockIdx.x, tid = threadIdx.x;
  const f4* HHT4 = (const f4*)HHT;
  f4* MEM4 = (f4*)MEM;
  int xcd = bid & 7, t2 = bid >> 3;
  int b = xcd*4 + (t2 & 3), ch8 = t2 >> 2;   // ch8 in 0..7

  // ---------- producer: head-proj column chunk ch8 for batch b ----------
  int base, count;
  if (ch8 < 4){ base = ch8*65; count = 65; }
  else        { base = 260 + (ch8-4)*64; count = 64; }
  if (tid < 128) ((f4*)hl)[tid] = HHT4[(size_t)t*4096 + tid*32 + b];
  if (t > 0){
    if (tid >= 128 && tid < 192){
      int i = tid - 128;
      int n = i >> 4, e4 = i & 15;
      wkp[n][e4] = ((const f4*)WKS)[(b*4 + n)*16 + e4];
    }
    if (tid >= 192 && tid < 196){
      int i = tid - 192;
      gmp[i] = WST[b*8 + i*2]; facp[i] = WST[b*8 + i*2 + 1];
    }
  }
  __syncthreads();
  {
    int q = tid & 3;
    const f4* h4 = (const f4*)hl + q*32;
    for (int cl = tid >> 2; cl < count; cl += 64){
      int col = base + cl;
      const f4* w4 = (const f4*)WT_HD2 + (size_t)col*128 + q*32;
      f4 a0 = {0.f,0.f,0.f,0.f}, a1 = {0.f,0.f,0.f,0.f};
      #pragma unroll 4
      for (int k4 = 0; k4 < 32; k4 += 2){
        a0 += w4[k4]   * h4[k4];
        a1 += w4[k4+1] * h4[k4+1];
      }
      redp[cl][q] = hsum(a0 + a1);
    }
  }
  __syncthreads();
  for (int cl = tid; cl < count; cl += 256){
    int col = base + cl;
    int n = col/129, c = col%129;
    HPT[col*32 + b] = redp[cl][0] + redp[cl][1] + redp[cl][2] + redp[cl][3]
                    + b_head[n*2115 + c];
  }
  __syncthreads();   // drains HPT stores (vmcnt) before the release-RMW
  if (tid == 0){
    __hip_atomic_fetch_add(CNT + b*16, 1u, __ATOMIC_ACQ_REL,
                           __HIP_MEMORY_SCOPE_AGENT);
    while (__hip_atomic_load(CNT + b*16, __ATOMIC_RELAXED,
                             __HIP_MEMORY_SCOPE_AGENT) < 8u*(unsigned)(t+1))
      __builtin_amdgcn_s_sleep(1);
    (void)__hip_atomic_load(CNT + b*16, __ATOMIC_ACQUIRE,
                            __HIP_MEMORY_SCOPE_AGENT);
  }
  __syncthreads();

  // ---------- consumer: deferred mem-update + scores + partials ----------
  for (int idx = tid; idx < 512; idx += 256){
    int kk = idx >> 6, e = idx & 63;
    int n = kk & 3;
    int c = (kk >= 4) ? (64 + e) : e;
    keys[kk][e] = HPT[(n*129 + c)*32 + b];
  }
  for (int sub = 0; sub < 4; ++sub){
    int ch = ch8*4 + sub;
    __syncthreads();
    for (int idx = tid; idx < 64*16; idx += 256){
      int m = idx >> 4, e4 = idx & 15;
      ((f4*)&mc[m][0])[e4] = MEM4[((size_t)b*MS + ch*64 + m)*16 + e4];
    }
    if (t > 0){
      int n = tid >> 6, m = tid & 63;
      float s = SW[((size_t)b*4 + n)*MS + ch*64 + m];
      ew[n][m] = __expf(s - gmp[n]) * facp[n];
    }
    __syncthreads();
    if (t > 0){
      for (int idx = tid; idx < 1024; idx += 256){
        int m = idx >> 4, e4 = idx & 15;
        f4 v = ((f4*)&mc[m][0])[e4];
        v += ew[0][m]*wkp[0][e4] + ew[1][m]*wkp[1][e4]
           + ew[2][m]*wkp[2][e4] + ew[3][m]*wkp[3][e4];
        ((f4*)&mc[m][0])[e4] = v;
        MEM4[((size_t)b*MS + ch*64 + m)*16 + e4] = v;
      }
      __syncthreads();
    }
    {
      int m = tid & 63, kp = tid >> 6;
      const f4* mrow4 = (const f4*)&mc[m][0];
      int k0 = kp*2, k1 = kp*2+1;
      f4 s0v = {0.f,0.f,0.f,0.f}, s1v = {0.f,0.f,0.f,0.f};
      #pragma unroll 4
      for (int e4 = 0; e4 < 16; ++e4){
        f4 mv = mrow4[e4];
        s0v += mv * (*(const f4*)&keys[k0][e4*4]);
        s1v += mv * (*(const f4*)&keys[k1][e4*4]);
      }
      float s0 = hsum(s0v)*0.125f, s1 = hsum(s1v)*0.125f;
      sc[k0][m] = s0; sc[k1][m] = s1;
      if (kp >= 2){
        float* swp = SW + ((size_t)b*4 + (k0-4))*MS + ch*64 + m;
        swp[0] = s0; swp[MS] = s1;
      }
    }
    __syncthreads();
    {
      int kk = tid >> 5, j = tid & 31;
      red[kk][j] = fmaxf(sc[kk][j], sc[kk][j+32]);
    }
    __syncthreads();
    if (tid < 8){
      float mx = red[tid][0];
      for (int j = 1; j < 32; ++j) mx = fmaxf(mx, red[tid][j]);
      cmx[tid] = mx;
    }
    __syncthreads();
    {
      int kk = tid >> 5, j = tid & 31;
      float m0 = cmx[kk];
      float e0 = __expf(sc[kk][j] - m0);
      float e1 = __expf(sc[kk][j+32] - m0);
      if (kk < 4){ sc[kk][j] = e0; sc[kk][j+32] = e1; }
      red[kk][j] = e0 + e1;
    }
    __syncthreads();
    if (tid < 8){
      float s = 0.f;
      for (int j = 0; j < 32; ++j) s += red[tid][j];
      float* pp = PART + (((size_t)b*NCH + ch)*8 + tid)*2;
      pp[0] = cmx[tid]; pp[1] = s;
    }
    {
      int n = tid >> 6, e = tid & 63;
      float pr = 0.f;
      for (int m = 0; m < 64; ++m) pr += sc[n][m] * mc[m][e];
      PREAD[(((size_t)b*NCH + ch)*4 + n)*64 + e] = pr;
    }
  }
  __syncthreads();   // drain PART/PREAD stores before the release-RMW
  if (tid == 0){
    unsigned old = __hip_atomic_fetch_add(CNT2 + b*16, 1u, __ATOMIC_ACQ_REL,
                                          __HIP_MEMORY_SCOPE_AGENT);
    lastf = ((old & 7u) == 7u) ? 1 : 0;
  }
  __syncthreads();
  if (!lastf) return;

  // ---------- last block of this b: read merge + write stats + wk save ----------
  if (tid < 4){
    int kk = 4 + tid;
    const float* pp = PART + ((size_t)b*NCH*8 + kk)*2;
    float mx = -1e30f;
    for (int ch = 0; ch < NCH; ++ch) mx = fmaxf(mx, pp[ch*16]);
    float d = 0.f;
    for (int ch = 0; ch < NCH; ++ch) d += pp[ch*16+1]*__expf(pp[ch*16] - mx);
    float st = sigm(HPT[(tid*129 + 128)*32 + b]);
    WST[b*8 + tid*2]     = mx;
    WST[b*8 + tid*2 + 1] = st / d;
  }
  {
    int n = tid >> 6, e = tid & 63;
    WKS[(b*4 + n)*64 + e] = HPT[(n*129 + 64 + e)*32 + b];
  }
  if (tid < 4){
    const float* pp = PART + ((size_t)b*NCH*8 + tid)*2;
    float mx = -1e30f;
    for (int ch = 0; ch < NCH; ++ch) mx = fmaxf(mx, pp[ch*16]);
    float d = 0.f;
    for (int ch = 0; ch < NCH; ++ch) d += pp[ch*16+1]*__expf(pp[ch*16] - mx);
    mgm[tid] = mx; mdn[tid] = d;
  }
  __syncthreads();
  {
    int n = tid >> 6, e = tid & 63;
    float gmn = mgm[n], dnn = mdn[n];
    float r = 0.f;
    for (int ch = 0; ch < NCH; ++ch){
      float cm = PART[(((size_t)b*NCH + ch)*8 + n)*2];
      r += PREAD[(((size_t)b*NCH + ch)*4 + n)*64 + e] * __expf(cm - gmn);
    }
    r /= dnn;
    int k = n*64 + e;
    READT[(k>>2)*128 + b*4 + (k&3)] = r;
    RHIST[((size_t)t*64 + (k>>2))*128 + b*4 + (k&3)] = r;
  }
  if (t == T-1){
    // copy this b's final h (128 f4)
    if (tid < 128)
      ((f4*)HF)[(size_t)b*128 + tid] = HHT4[((size_t)(T-1)*128 + tid)*32 + b];
  }
}

// ---------------- final mem-update flush for t = T-1 (256 blocks) ----------------
__global__ __launch_bounds__(256) void k_flush(
    float* __restrict__ MEM, const float* __restrict__ SW,
    const float* __restrict__ WST, const float* __restrict__ WKS)
{
  __shared__ float gm[4], fac[4];
  __shared__ f4 wk4[4][16];
  __shared__ float ew[4][256];
  const int bid = blockIdx.x, tid = threadIdx.x;
  int xcd = bid & 7, t2 = bid >> 3;
  int b = xcd*4 + (t2 & 3), sub = t2 >> 2;
  if (tid < 4){ gm[tid] = WST[b*8 + tid*2]; fac[tid] = WST[b*8 + tid*2 + 1]; }
  if (tid < 64){
    int n = tid >> 4, e4 = tid & 15;
    wk4[n][e4] = ((const f4*)WKS)[(b*4 + n)*16 + e4];
  }
  __syncthreads();
  for (int idx = tid; idx < 1024; idx += 256){
    int n = idx >> 8, m = idx & 255;
    float s = SW[((size_t)b*4 + n)*MS + sub*256 + m];
    ew[n][m] = __expf(s - gm[n]) * fac[n];
  }
  __syncthreads();
  {
    int e4 = tid & 15, ms = tid >> 4;
    f4 k0 = wk4[0][e4], k1 = wk4[1][e4], k2 = wk4[2][e4], k3 = wk4[3][e4];
    #pragma unroll 2
    for (int it = 0; it < 16; ++it){
      int m = it*16 + ms;
      float w0 = ew[0][m], w1 = ew[1][m];
      float w2 = ew[2][m], w3 = ew[3][m];
      f4* p = (f4*)MEM + ((size_t)b*MS + sub*256 + m)*16 + e4;
      f4 v = *p;
      v += w0*k0 + w1*k1 + w2*k2 + w3*k3;
      *p = v;
    }
  }
}

// ---------------- final output GEMM (256 blocks) ----------------
__global__ __launch_bounds__(256) void k_out(
    const float* __restrict__ HHT, const float* __restrict__ RHIST,
    const float* __restrict__ WT_OUT, const float* __restrict__ b_out,
    float* __restrict__ out)
{
  __shared__ float A[16][260];
  const int bid = blockIdx.x, tid = threadIdx.x;
  const f4* HHT4 = (const f4*)HHT;
  const f4* RHIST4 = (const f4*)RHIST;
  const f4* W4 = (const f4*)WT_OUT;
  int nt = bid & 3, mt = bid >> 2;
  int rl = tid & 15, og = tid >> 4;
  int o = nt*64 + og*4, o4 = o >> 2;
  f4 a0 = {0.f,0.f,0.f,0.f}, a1 = a0, a2 = a0, a3 = a0;
  for (int kc = 0; kc < 3; ++kc){
    __syncthreads();
    for (int idx = tid; idx < 1024; idx += 256){
      int r = idx >> 6, k4 = idx & 63;
      int row = mt*16 + r;
      int bb = row >> 5, tt = row & 31;
      int kg4 = kc*64 + k4;
      f4 v = (kg4 < 128)
        ? HHT4[((size_t)tt*128 + kg4)*32 + bb]
        : RHIST4[((size_t)tt*64 + (kg4-128))*32 + bb];
      *(f4*)&A[r][k4*4] = v;
    }
    __syncthreads();
    const float* Ar = &A[rl][0];
    const f4* wp = W4 + (size_t)kc*256*64 + o4;
    #pragma unroll 2
    for (int k = 0; k < 256; k += 4){
      a0 += Ar[k]   * wp[(size_t)(k)*64];
      a1 += Ar[k+1] * wp[(size_t)(k+1)*64];
      a2 += Ar[k+2] * wp[(size_t)(k+2)*64];
      a3 += Ar[k+3] * wp[(size_t)(k+3)*64];
    }
  }
  int row = mt*16 + rl;
  f4 accv = (a0 + a1) + (a2 + a3);
  accv += *(const f4*)(b_out + o);
  *(f4*)(out + (size_t)row*O_DIM + o) = accv;
}

extern "C" void kernel_launch(void* const* d_in, const int* in_sizes, int n_in,
                              void* d_out, int out_size, void* d_ws, size_t ws_size,
                              hipStream_t stream)
{
  const float* x      = (const float*)d_in[0];
  const float* W_ih   = (const float*)d_in[1];
  const float* W_hh   = (const float*)d_in[2];
  const float* b_ih   = (const float*)d_in[3];
  const float* b_hh   = (const float*)d_in[4];
  const float* W_head = (const float*)d_in[5];
  const float* b_head = (const float*)d_in[6];
  const float* W_out  = (const float*)d_in[7];
  const float* b_out  = (const float*)d_in[8];

  float* out = (float*)d_out;
  float* MEM = out + B*T*O_DIM;
  float* HF  = MEM + (size_t)B*MS*HS;
  float* CF  = HF + B*H_DIM;

  float* ws      = (float*)d_ws;
  float* WT_HD2  = ws;                          // 520*512
  float* WT_OUT  = WT_HD2 + 520*512;            // 768*256
  float* XT      = WT_OUT + 768*256;            // 262144
  float* SW      = XT     + 262144;             // 262144
  float* PART    = SW     + 262144;             // 16384
  float* PREAD   = PART   + 16384;              // 262144
  float* HPT     = PREAD  + 262144;             // 16640
  float* READT   = HPT    + 16640;              // 8192
  float* HHT     = READT  + 8192;               // 524288
  float* RHIST   = HHT    + 524288;             // 262144
  float* WST     = RHIST  + 262144;             // 256
  float* WKS     = WST    + 256;                // 8192
  unsigned* CNT  = (unsigned*)(WKS + 8192);     // 32*16 u32
  unsigned* CNT2 = CNT + 32*16;                 // 32*16 u32

  (void)hipMemsetAsync(MEM, 0, ((size_t)B*MS*HS + 2*B*H_DIM)*sizeof(float), stream);
  (void)hipMemsetAsync(READT, 0, (size_t)8192*sizeof(float), stream);
  (void)hipMemsetAsync(CNT, 0, 2*32*16*sizeof(unsigned), stream);

  k_ghead<<<1040, 256, 0, stream>>>(WT_HD2, W_head);
  k_transpose_t<<<dim3(8, 24), 256, 0, stream>>>(WT_OUT, W_out, 256, 768);
  k_xt<<<256, 256, 0, stream>>>((f4*)XT, x);

  for (int t = 0; t < T; ++t){
    k_A<<<256, 256, 0, stream>>>((const f4*)XT, W_ih, W_hh, b_ih, b_hh,
                                 (const f4*)READT, HHT, CF, t);
    k_BCD<<<256, 256, 0, stream>>>(MEM, HHT, WT_HD2, b_head, HPT, SW, PART,
                                   PREAD, READT, RHIST, WST, WKS, HF,
                                   CNT, CNT2, t);
  }
  k_flush<<<256, 256, 0, stream>>>(MEM, SW, WST, WKS);
  k_out<<<256, 256, 0, stream>>>(HHT, RHIST, WT_OUT, b_out, out);
}

// Round 12
// 1513.608 us; speedup vs baseline: 2.5924x; 1.2991x over previous
//
#include <hip/hip_runtime.h>
#include <math.h>

#define B 32
#define T 32
#define O_DIM 256
#define H_DIM 512
#define HS 64
#define MS 2048
#define NCOL 516
#define NCH 32          // 64-row softmax chunks

typedef __attribute__((ext_vector_type(4))) float f4;

__device__ __forceinline__ float sigm(float x){ return 1.0f/(1.0f+__expf(-x)); }
__device__ __forceinline__ float hsum(f4 v){ return (v.x + v.y) + (v.z + v.w); }

// ---------------- prep kernels ----------------
__global__ __launch_bounds__(256) void k_transpose_t(float* __restrict__ dst,
                                                     const float* __restrict__ src,
                                                     int N, int K){
  __shared__ float tile[32][33];
  int jb = blockIdx.x*32, kb = blockIdx.y*32;
  int tj = threadIdx.x & 31, tk = threadIdx.x >> 5;
  #pragma unroll
  for (int p = 0; p < 4; ++p){
    int j = jb + tk + p*8, k = kb + tj;
    if (j < N && k < K) tile[tk + p*8][tj] = src[j*K + k];
  }
  __syncthreads();
  #pragma unroll
  for (int p = 0; p < 4; ++p){
    int k = kb + tk + p*8, j = jb + tj;
    if (j < N && k < K) dst[k*N + j] = tile[tj][tk + p*8];
  }
}

__global__ __launch_bounds__(256) void k_ghead(float* __restrict__ dst,
                                               const float* __restrict__ W_head){
  int idx = blockIdx.x*256 + threadIdx.x;     // col*512 + k
  if (idx >= 520*512) return;
  int col = idx >> 9, k = idx & 511;
  float v = 0.f;
  if (col < NCOL){ int n = col/129, c = col%129; v = W_head[((size_t)n*2115 + c)*512 + k]; }
  dst[idx] = v;
}

__global__ __launch_bounds__(256) void k_xt(f4* __restrict__ XT4,
                                            const float* __restrict__ x){
  int idx = blockIdx.x*256 + threadIdx.x;     // t*2048 + k4*32 + b
  int b = idx & 31, k4 = (idx >> 5) & 63, t = idx >> 11;
  XT4[idx] = ((const f4*)x)[(size_t)(b*T + t)*64 + k4];
}

// ---------------- K1: gates GEMM + LSTM (512 blocks, 4 rows each) ----------------
// block bid handles j = bid for all 4 gates; slot = (gate, khalf) per 32 threads.
__global__ __launch_bounds__(256) void k_A(
    const f4* __restrict__ XT4, const float* __restrict__ W_ih,
    const float* __restrict__ W_hh, const float* __restrict__ b_ih,
    const float* __restrict__ b_hh, const f4* __restrict__ READT4,
    float* __restrict__ HHT, float* __restrict__ CF, int t)
{
  __shared__ f4 WS[4*256];     // 4 rows x (128 f4 W_ih + 128 f4 W_hh) = 16 KB
  __shared__ float gl[8][33];
  const int bid = blockIdx.x, tid = threadIdx.x;
  const f4* HHT4 = (const f4*)HHT;
  for (int idx = tid; idx < 1024; idx += 256){
    int gate = idx >> 8, q = idx & 255;
    int row = gate*512 + bid;
    WS[idx] = (q < 128) ? ((const f4*)W_ih)[(size_t)row*128 + q]
                        : ((const f4*)W_hh)[(size_t)row*128 + (q - 128)];
  }
  __syncthreads();
  {
    int b = tid & 31, slot = tid >> 5;
    int gate = slot & 3, kh = slot >> 2;
    const f4* w = WS + gate*256;
    f4 a0 = {0.f,0.f,0.f,0.f}, a1 = {0.f,0.f,0.f,0.f};
    if (kh == 0){
      const f4* xt4 = XT4 + (size_t)t*2048;
      #pragma unroll 4
      for (int k4 = 0; k4 < 64; k4 += 2){
        a0 += w[k4]   * xt4[k4*32 + b];
        a1 += w[k4+1] * xt4[(k4+1)*32 + b];
      }
      #pragma unroll 4
      for (int k4 = 0; k4 < 64; k4 += 2){
        a0 += w[64+k4]   * READT4[k4*32 + b];
        a1 += w[64+k4+1] * READT4[(k4+1)*32 + b];
      }
    } else if (t > 0){
      const f4* ht4 = HHT4 + (size_t)(t-1)*4096;
      #pragma unroll 4
      for (int k4 = 0; k4 < 128; k4 += 2){
        a0 += w[128+k4]   * ht4[k4*32 + b];
        a1 += w[128+k4+1] * ht4[(k4+1)*32 + b];
      }
    }
    float acc = hsum(a0 + a1);
    if (kh == 0) acc += b_ih[gate*512 + bid] + b_hh[gate*512 + bid];
    gl[slot][b] = acc;
  }
  __syncthreads();
  if (tid < 32){
    int b2 = tid, j = bid;
    float gi = gl[0][b2] + gl[4][b2];
    float gf = gl[1][b2] + gl[5][b2];
    float gg = gl[2][b2] + gl[6][b2];
    float go = gl[3][b2] + gl[7][b2];
    float c = sigm(gf)*CF[b2*512+j] + sigm(gi)*tanhf(gg);
    float h = sigm(go)*tanhf(c);
    CF[b2*512+j] = c;
    HHT[((size_t)t*128 + (j>>2))*128 + b2*4 + (j&3)] = h;
  }
}

// ---------------- K2: head projection (130 blocks, 4 cols x 32 b) ----------------
__global__ __launch_bounds__(256) void k_B(
    const float* __restrict__ HHT, const float* __restrict__ WT_HD2,
    const float* __restrict__ b_head, float* __restrict__ HPT, int t)
{
  __shared__ float red[256];
  const int bid = blockIdx.x, tid = threadIdx.x;
  const f4* HHT4 = (const f4*)HHT;
  int b = tid & 31, cs = (tid>>5)&3, khalf = tid>>7;
  int col = bid*4 + cs;
  const f4* hT4 = HHT4 + (size_t)t*4096 + khalf*2048;
  const f4* w4  = (const f4*)(WT_HD2 + (size_t)col*512 + khalf*256);
  f4 acc4 = {0.f, 0.f, 0.f, 0.f};
  #pragma unroll 4
  for (int k4 = 0; k4 < 64; ++k4)
    acc4 += w4[k4] * hT4[k4*32 + b];
  red[tid] = hsum(acc4);
  __syncthreads();
  if (khalf == 0){
    float v = red[tid] + red[tid + 128];
    if (col < NCOL){ int n = col/129, c = col%129; v += b_head[n*2115 + c]; }
    HPT[col*32 + b] = v;
  }
}

// ---- K3 (512 blocks): deferred mem-update + scores + partials; last-of-16 merges ----
__global__ __launch_bounds__(256) void k_CD(
    float* __restrict__ MEM, const float* __restrict__ HHT,
    const float* __restrict__ HPT, float* __restrict__ SW,
    float* __restrict__ PART, float* __restrict__ PREAD,
    float* __restrict__ READT, float* __restrict__ RHIST,
    float* __restrict__ WST, float* __restrict__ WKS,
    float* __restrict__ HF, unsigned* __restrict__ CNT2, int t)
{
  __shared__ float keys[8][64];
  __shared__ float mc[64][68];
  __shared__ float sc[8][64];
  __shared__ float red[8][32];
  __shared__ float cmx[8];
  __shared__ float ew[4][64];
  __shared__ f4 wkp[4][16];
  __shared__ float gmp[4], facp[4];
  __shared__ float mgm[4], mdn[4];
  __shared__ int lastf;
  const int bid = blockIdx.x, tid = threadIdx.x;
  const f4* HHT4 = (const f4*)HHT;
  f4* MEM4 = (f4*)MEM;
  int xcd = bid & 7, t2 = bid >> 3;
  int b = xcd*4 + (t2 & 3), chg = t2 >> 2;    // chg in 0..15, chunks chg*2 + {0,1}

  for (int idx = tid; idx < 512; idx += 256){
    int kk = idx >> 6, e = idx & 63;
    int n = kk & 3;
    int c = (kk >= 4) ? (64 + e) : e;
    keys[kk][e] = HPT[(n*129 + c)*32 + b];
  }
  if (t > 0){
    if (tid >= 128 && tid < 192){
      int i = tid - 128;
      int n = i >> 4, e4 = i & 15;
      wkp[n][e4] = ((const f4*)WKS)[(b*4 + n)*16 + e4];
    }
    if (tid >= 192 && tid < 196){
      int i = tid - 192;
      gmp[i] = WST[b*8 + i*2]; facp[i] = WST[b*8 + i*2 + 1];
    }
  }
  for (int sub = 0; sub < 2; ++sub){
    int ch = chg*2 + sub;
    __syncthreads();
    for (int idx = tid; idx < 64*16; idx += 256){
      int m = idx >> 4, e4 = idx & 15;
      ((f4*)&mc[m][0])[e4] = MEM4[((size_t)b*MS + ch*64 + m)*16 + e4];
    }
    if (t > 0){
      int n = tid >> 6, m = tid & 63;
      float s = SW[((size_t)b*4 + n)*MS + ch*64 + m];
      ew[n][m] = __expf(s - gmp[n]) * facp[n];
    }
    __syncthreads();
    if (t > 0){
      for (int idx = tid; idx < 1024; idx += 256){
        int m = idx >> 4, e4 = idx & 15;
        f4 v = ((f4*)&mc[m][0])[e4];
        v += ew[0][m]*wkp[0][e4] + ew[1][m]*wkp[1][e4]
           + ew[2][m]*wkp[2][e4] + ew[3][m]*wkp[3][e4];
        ((f4*)&mc[m][0])[e4] = v;
        MEM4[((size_t)b*MS + ch*64 + m)*16 + e4] = v;
      }
      __syncthreads();
    }
    {
      int m = tid & 63, kp = tid >> 6;
      const f4* mrow4 = (const f4*)&mc[m][0];
      int k0 = kp*2, k1 = kp*2+1;
      f4 s0v = {0.f,0.f,0.f,0.f}, s1v = {0.f,0.f,0.f,0.f};
      #pragma unroll 4
      for (int e4 = 0; e4 < 16; ++e4){
        f4 mv = mrow4[e4];
        s0v += mv * (*(const f4*)&keys[k0][e4*4]);
        s1v += mv * (*(const f4*)&keys[k1][e4*4]);
      }
      float s0 = hsum(s0v)*0.125f, s1 = hsum(s1v)*0.125f;
      sc[k0][m] = s0; sc[k1][m] = s1;
      if (kp >= 2){
        float* swp = SW + ((size_t)b*4 + (k0-4))*MS + ch*64 + m;
        swp[0] = s0; swp[MS] = s1;
      }
    }
    __syncthreads();
    {
      int kk = tid >> 5, j = tid & 31;
      red[kk][j] = fmaxf(sc[kk][j], sc[kk][j+32]);
    }
    __syncthreads();
    if (tid < 8){
      float mx = red[tid][0];
      for (int j = 1; j < 32; ++j) mx = fmaxf(mx, red[tid][j]);
      cmx[tid] = mx;
    }
    __syncthreads();
    {
      int kk = tid >> 5, j = tid & 31;
      float m0 = cmx[kk];
      float e0 = __expf(sc[kk][j] - m0);
      float e1 = __expf(sc[kk][j+32] - m0);
      if (kk < 4){ sc[kk][j] = e0; sc[kk][j+32] = e1; }
      red[kk][j] = e0 + e1;
    }
    __syncthreads();
    if (tid < 8){
      float s = 0.f;
      for (int j = 0; j < 32; ++j) s += red[tid][j];
      float* pp = PART + (((size_t)b*NCH + ch)*8 + tid)*2;
      pp[0] = cmx[tid]; pp[1] = s;
    }
    {
      int n = tid >> 6, e = tid & 63;
      float pr = 0.f;
      for (int m = 0; m < 64; ++m) pr += sc[n][m] * mc[m][e];
      PREAD[(((size_t)b*NCH + ch)*4 + n)*64 + e] = pr;
    }
  }
  __syncthreads();   // drain PART/PREAD/SW stores before the release-RMW
  if (tid == 0){
    unsigned old = __hip_atomic_fetch_add(CNT2 + b*16, 1u, __ATOMIC_ACQ_REL,
                                          __HIP_MEMORY_SCOPE_AGENT);
    lastf = ((old & 15u) == 15u) ? 1 : 0;
  }
  __syncthreads();
  if (!lastf) return;

  // ---------- last block of this b: read merge + write stats + wk save ----------
  if (tid < 4){
    int kk = 4 + tid;
    const float* pp = PART + ((size_t)b*NCH*8 + kk)*2;
    float mx = -1e30f;
    for (int ch = 0; ch < NCH; ++ch) mx = fmaxf(mx, pp[ch*16]);
    float d = 0.f;
    for (int ch = 0; ch < NCH; ++ch) d += pp[ch*16+1]*__expf(pp[ch*16] - mx);
    float st = sigm(HPT[(tid*129 + 128)*32 + b]);
    WST[b*8 + tid*2]     = mx;
    WST[b*8 + tid*2 + 1] = st / d;
  }
  {
    int n = tid >> 6, e = tid & 63;
    WKS[(b*4 + n)*64 + e] = HPT[(n*129 + 64 + e)*32 + b];
  }
  if (tid < 4){
    const float* pp = PART + ((size_t)b*NCH*8 + tid)*2;
    float mx = -1e30f;
    for (int ch = 0; ch < NCH; ++ch) mx = fmaxf(mx, pp[ch*16]);
    float d = 0.f;
    for (int ch = 0; ch < NCH; ++ch) d += pp[ch*16+1]*__expf(pp[ch*16] - mx);
    mgm[tid] = mx; mdn[tid] = d;
  }
  __syncthreads();
  {
    int n = tid >> 6, e = tid & 63;
    float gmn = mgm[n], dnn = mdn[n];
    float r = 0.f;
    for (int ch = 0; ch < NCH; ++ch){
      float cm = PART[(((size_t)b*NCH + ch)*8 + n)*2];
      r += PREAD[(((size_t)b*NCH + ch)*4 + n)*64 + e] * __expf(cm - gmn);
    }
    r /= dnn;
    int k = n*64 + e;
    READT[(k>>2)*128 + b*4 + (k&3)] = r;
    RHIST[((size_t)t*64 + (k>>2))*128 + b*4 + (k&3)] = r;
  }
  if (t == T-1){
    if (tid < 128)
      ((f4*)HF)[(size_t)b*128 + tid] = HHT4[((size_t)(T-1)*128 + tid)*32 + b];
  }
}

// ---------------- final mem-update flush for t = T-1 (256 blocks) ----------------
__global__ __launch_bounds__(256) void k_flush(
    float* __restrict__ MEM, const float* __restrict__ SW,
    const float* __restrict__ WST, const float* __restrict__ WKS)
{
  __shared__ float gm[4], fac[4];
  __shared__ f4 wk4[4][16];
  __shared__ float ew[4][256];
  const int bid = blockIdx.x, tid = threadIdx.x;
  int xcd = bid & 7, t2 = bid >> 3;
  int b = xcd*4 + (t2 & 3), sub = t2 >> 2;
  if (tid < 4){ gm[tid] = WST[b*8 + tid*2]; fac[tid] = WST[b*8 + tid*2 + 1]; }
  if (tid < 64){
    int n = tid >> 4, e4 = tid & 15;
    wk4[n][e4] = ((const f4*)WKS)[(b*4 + n)*16 + e4];
  }
  __syncthreads();
  for (int idx = tid; idx < 1024; idx += 256){
    int n = idx >> 8, m = idx & 255;
    float s = SW[((size_t)b*4 + n)*MS + sub*256 + m];
    ew[n][m] = __expf(s - gm[n]) * fac[n];
  }
  __syncthreads();
  {
    int e4 = tid & 15, ms = tid >> 4;
    f4 k0 = wk4[0][e4], k1 = wk4[1][e4], k2 = wk4[2][e4], k3 = wk4[3][e4];
    #pragma unroll 2
    for (int it = 0; it < 16; ++it){
      int m = it*16 + ms;
      float w0 = ew[0][m], w1 = ew[1][m];
      float w2 = ew[2][m], w3 = ew[3][m];
      f4* p = (f4*)MEM + ((size_t)b*MS + sub*256 + m)*16 + e4;
      f4 v = *p;
      v += w0*k0 + w1*k1 + w2*k2 + w3*k3;
      *p = v;
    }
  }
}

// ---------------- final output GEMM (256 blocks) ----------------
__global__ __launch_bounds__(256) void k_out(
    const float* __restrict__ HHT, const float* __restrict__ RHIST,
    const float* __restrict__ WT_OUT, const float* __restrict__ b_out,
    float* __restrict__ out)
{
  __shared__ float A[16][260];
  const int bid = blockIdx.x, tid = threadIdx.x;
  const f4* HHT4 = (const f4*)HHT;
  const f4* RHIST4 = (const f4*)RHIST;
  const f4* W4 = (const f4*)WT_OUT;
  int nt = bid & 3, mt = bid >> 2;
  int rl = tid & 15, og = tid >> 4;
  int o = nt*64 + og*4, o4 = o >> 2;
  f4 a0 = {0.f,0.f,0.f,0.f}, a1 = a0, a2 = a0, a3 = a0;
  for (int kc = 0; kc < 3; ++kc){
    __syncthreads();
    for (int idx = tid; idx < 1024; idx += 256){
      int r = idx >> 6, k4 = idx & 63;
      int row = mt*16 + r;
      int bb = row >> 5, tt = row & 31;
      int kg4 = kc*64 + k4;
      f4 v = (kg4 < 128)
        ? HHT4[((size_t)tt*128 + kg4)*32 + bb]
        : RHIST4[((size_t)tt*64 + (kg4-128))*32 + bb];
      *(f4*)&A[r][k4*4] = v;
    }
    __syncthreads();
    const float* Ar = &A[rl][0];
    const f4* wp = W4 + (size_t)kc*256*64 + o4;
    #pragma unroll 2
    for (int k = 0; k < 256; k += 4){
      a0 += Ar[k]   * wp[(size_t)(k)*64];
      a1 += Ar[k+1] * wp[(size_t)(k+1)*64];
      a2 += Ar[k+2] * wp[(size_t)(k+2)*64];
      a3 += Ar[k+3] * wp[(size_t)(k+3)*64];
    }
  }
  int row = mt*16 + rl;
  f4 accv = (a0 + a1) + (a2 + a3);
  accv += *(const f4*)(b_out + o);
  *(f4*)(out + (size_t)row*O_DIM + o) = accv;
}

extern "C" void kernel_launch(void* const* d_in, const int* in_sizes, int n_in,
                              void* d_out, int out_size, void* d_ws, size_t ws_size,
                              hipStream_t stream)
{
  const float* x      = (const float*)d_in[0];
  const float* W_ih   = (const float*)d_in[1];
  const float* W_hh   = (const float*)d_in[2];
  const float* b_ih   = (const float*)d_in[3];
  const float* b_hh   = (const float*)d_in[4];
  const float* W_head = (const float*)d_in[5];
  const float* b_head = (const float*)d_in[6];
  const float* W_out  = (const float*)d_in[7];
  const float* b_out  = (const float*)d_in[8];

  float* out = (float*)d_out;
  float* MEM = out + B*T*O_DIM;
  float* HF  = MEM + (size_t)B*MS*HS;
  float* CF  = HF + B*H_DIM;

  float* ws      = (float*)d_ws;
  float* WT_HD2  = ws;                          // 520*512
  float* WT_OUT  = WT_HD2 + 520*512;            // 768*256
  float* XT      = WT_OUT + 768*256;            // 262144
  float* SW      = XT     + 262144;             // 262144
  float* PART    = SW     + 262144;             // 16384
  float* PREAD   = PART   + 16384;              // 262144
  float* HPT     = PREAD  + 262144;             // 16640
  float* READT   = HPT    + 16640;              // 8192
  float* HHT     = READT  + 8192;               // 524288
  float* RHIST   = HHT    + 524288;             // 262144
  float* WST     = RHIST  + 262144;             // 256
  float* WKS     = WST    + 256;                // 8192
  unsigned* CNT2 = (unsigned*)(WKS + 8192);     // 32*16 u32

  (void)hipMemsetAsync(MEM, 0, ((size_t)B*MS*HS + 2*B*H_DIM)*sizeof(float), stream);
  (void)hipMemsetAsync(READT, 0, (size_t)8192*sizeof(float), stream);
  (void)hipMemsetAsync(CNT2, 0, 32*16*sizeof(unsigned), stream);

  k_ghead<<<1040, 256, 0, stream>>>(WT_HD2, W_head);
  k_transpose_t<<<dim3(8, 24), 256, 0, stream>>>(WT_OUT, W_out, 256, 768);
  k_xt<<<256, 256, 0, stream>>>((f4*)XT, x);

  for (int t = 0; t < T; ++t){
    k_A<<<512, 256, 0, stream>>>((const f4*)XT, W_ih, W_hh, b_ih, b_hh,
                                 (const f4*)READT, HHT, CF, t);
    k_B<<<130, 256, 0, stream>>>(HHT, WT_HD2, b_head, HPT, t);
    k_CD<<<512, 256, 0, stream>>>(MEM, HHT, HPT, SW, PART, PREAD, READT,
                                  RHIST, WST, WKS, HF, CNT2, t);
  }
  k_flush<<<256, 256, 0, stream>>>(MEM, SW, WST, WKS);
  k_out<<<256, 256, 0, stream>>>(HHT, RHIST, WT_OUT, b_out, out);
}